// Round 8
// baseline (145.739 us; speedup 1.0000x reference)
//
#include <hip/hip_runtime.h>
#include <hip/hip_bf16.h>

// MHA: B=8, S=1024, D=1024, H=16, DH=64.
// R8: software-pipelined attention. PV is delayed one t-iteration: iteration i
// computes QK(i)->exp->Pa_i while issuing PV(i-1)+denominator MFMAs (on Pa_{i-1},
// held in registers) between the QK MFMAs and their dependent exp VALU — giving
// the scheduler independent MFMA work to co-issue against the quarter-rate
// v_exp_f32 burst. V is triple-buffered (lives 2 iters), K double-buffered.
// All-k32 phase-split QK (R7), conflict-free swizzles, g=4, 512 blocks.

constexpr int NB = 8, NS = 1024, ND = 1024, NH = 16, NDH = 64;

typedef __bf16 bf16x8 __attribute__((ext_vector_type(8)));
typedef float f32x4 __attribute__((ext_vector_type(4)));

__device__ __forceinline__ f32x4 mfma16(bf16x8 a, bf16x8 b, f32x4 c) {
  return __builtin_amdgcn_mfma_f32_16x16x32_bf16(a, b, c, 0, 0, 0);
}

__device__ __forceinline__ float fast_exp2(float x) {
#if __has_builtin(__builtin_amdgcn_exp2f)
  return __builtin_amdgcn_exp2f(x);   // raw v_exp_f32
#else
  return __builtin_exp2f(x);
#endif
}

__device__ __forceinline__ bf16x8 cvt2bf8(float4 lo, float4 hi) {
  bf16x8 r;
  r[0] = (__bf16)lo.x; r[1] = (__bf16)lo.y; r[2] = (__bf16)lo.z; r[3] = (__bf16)lo.w;
  r[4] = (__bf16)hi.x; r[5] = (__bf16)hi.y; r[6] = (__bf16)hi.z; r[7] = (__bf16)hi.w;
  return r;
}

__device__ __forceinline__ void gload16(const __hip_bfloat16* g, __hip_bfloat16* l) {
  __builtin_amdgcn_global_load_lds(
      (const __attribute__((address_space(1))) void*)g,
      (__attribute__((address_space(3))) void*)l, 16, 0, 0);
}

// Pack two f32 into a u32 of bf16s (lo in low half): round-half-up + byte perm.
__device__ __forceinline__ unsigned pack_bf16(float hi, float lo) {
  unsigned uh = __builtin_bit_cast(unsigned, hi) + 0x8000u;
  unsigned ul = __builtin_bit_cast(unsigned, lo) + 0x8000u;
  return __builtin_amdgcn_perm(uh, ul, 0x07060302u);
}

// ---------------- QKV projection (unchanged from R3) ----------------
__global__ __launch_bounds__(256) void qkv_proj_kernel(
    const float* __restrict__ x,
    const float* __restrict__ Wq, const float* __restrict__ bq,
    const float* __restrict__ Wk, const float* __restrict__ bk,
    const float* __restrict__ Wv, const float* __restrict__ bv,
    __hip_bfloat16* __restrict__ Qo, __hip_bfloat16* __restrict__ Ko,
    __hip_bfloat16* __restrict__ Vt) {
  __shared__ __align__(16) __hip_bfloat16 Wlds[3][NDH][72];
  const int tid = threadIdx.x;
  const int wave = tid >> 6, lane = tid & 63;
  const int m = lane & 15, quad = lane >> 4;
  const int h = blockIdx.x & (NH - 1);
  const int sblk = blockIdx.x >> 4;

  const float* Ws[3] = {Wq + h * 4096, Wk + h * 4096, Wv + h * 4096};
#pragma unroll
  for (int mt = 0; mt < 3; mt++) {
#pragma unroll
    for (int p = 0; p < 4; p++) {
      int idx = (p * 256 + tid) * 4;
      float4 v = *(const float4*)(Ws[mt] + idx);
      __align__(8) __hip_bfloat16 t4[4] = {
          __float2bfloat16(v.x), __float2bfloat16(v.y),
          __float2bfloat16(v.z), __float2bfloat16(v.w)};
      *(uint2*)&Wlds[mt][idx >> 6][idx & 63] = *(const uint2*)t4;
    }
  }
  __syncthreads();

  float bq4[4][4], bk4[4][4], bvv[4];
#pragma unroll
  for (int nt = 0; nt < 4; nt++) {
    float4 a = *(const float4*)(bq + h * 64 + nt * 16 + quad * 4);
    float4 c = *(const float4*)(bk + h * 64 + nt * 16 + quad * 4);
    bq4[nt][0] = a.x; bq4[nt][1] = a.y; bq4[nt][2] = a.z; bq4[nt][3] = a.w;
    bk4[nt][0] = c.x; bk4[nt][1] = c.y; bk4[nt][2] = c.z; bk4[nt][3] = c.w;
    bvv[nt] = bv[h * 64 + nt * 16 + m];
  }

  const int rowbase = sblk * 256 + wave * 64;
  bf16x8 Xf[4][2];
#pragma unroll
  for (int st = 0; st < 4; st++) {
    const float* xp = x + (size_t)(rowbase + st * 16 + m) * ND + h * NDH + quad * 8;
#pragma unroll
    for (int c = 0; c < 2; c++) {
      float4 lo = *(const float4*)(xp + c * 32);
      float4 hi = *(const float4*)(xp + c * 32 + 4);
      Xf[st][c] = cvt2bf8(lo, hi);
    }
  }

  const int b = rowbase >> 10;
  const int s0 = rowbase & 1023;
  const float qscale = 0.18033688011112042f;  // log2(e)/sqrt(64)

#pragma unroll
  for (int mt = 0; mt < 3; mt++) {
#pragma unroll
    for (int nt = 0; nt < 4; nt++) {
      bf16x8 w0 = *(const bf16x8*)&Wlds[mt][nt * 16 + m][quad * 8];
      bf16x8 w1 = *(const bf16x8*)&Wlds[mt][nt * 16 + m][32 + quad * 8];
#pragma unroll
      for (int st = 0; st < 4; st++) {
        f32x4 acc = {0.f, 0.f, 0.f, 0.f};
        if (mt < 2) {
          acc = mfma16(w0, Xf[st][0], acc);
          acc = mfma16(w1, Xf[st][1], acc);
          const int srow = s0 + st * 16 + m;
          __align__(8) __hip_bfloat16 t4[4];
          if (mt == 0) {
#pragma unroll
            for (int r = 0; r < 4; r++)
              t4[r] = __float2bfloat16((acc[r] + bq4[nt][r]) * qscale);
            *(uint2*)(Qo + ((size_t)(b * NH + h) * NS + srow) * NDH +
                      nt * 16 + quad * 4) = *(const uint2*)t4;
          } else {
#pragma unroll
            for (int r = 0; r < 4; r++)
              t4[r] = __float2bfloat16(acc[r] + bk4[nt][r]);
            *(uint2*)(Ko + ((size_t)(b * NH + h) * NS + srow) * NDH +
                      nt * 16 + quad * 4) = *(const uint2*)t4;
          }
        } else {
          acc = mfma16(Xf[st][0], w0, acc);
          acc = mfma16(Xf[st][1], w1, acc);
          __align__(8) __hip_bfloat16 t4[4];
#pragma unroll
          for (int r = 0; r < 4; r++) t4[r] = __float2bfloat16(acc[r] + bvv[nt]);
          *(uint2*)(Vt + ((size_t)(b * NH + h) * NDH + nt * 16 + m) * NS + s0 +
                    st * 16 + quad * 4) = *(const uint2*)t4;
        }
      }
    }
  }
}

// ---------------- Attention ----------------
__global__ __launch_bounds__(256, 2) void attn_kernel(
    const __hip_bfloat16* __restrict__ Q,   // [B,H,S,DH] pre-scaled
    const __hip_bfloat16* __restrict__ K,   // [B,H,S,DH]
    const __hip_bfloat16* __restrict__ Vt,  // [B,H,DH,S]
    float* __restrict__ out) {              // [B,S,D]
  // K dbuf (16 KB) + V triple-buffer (24 KB) = 40 KB. Unpadded, swizzled:
  // K: f_K=(row&3)|((row&8)>>1); V: f_V=row&7.
  __shared__ __align__(16) __hip_bfloat16 Kt[2][64][64];
  __shared__ __align__(16) __hip_bfloat16 Vl[3][64][64];

  const int tid = threadIdx.x;
  const int wave = tid >> 6, lane = tid & 63;
  const int m = lane & 15, quad = lane >> 4;

  const int xcd = blockIdx.x & 7;
  const int j = blockIdx.x >> 3;          // 0..63
  const int bh = xcd * 16 + (j & 15);
  const int qblk = j >> 4;                // 0..3
  const int qbase = qblk * 256 + wave * 64;  // 64 q-rows per wave (4 g of 16)

  const __hip_bfloat16* Qp = Q + (size_t)bh * NS * NDH;
  const __hip_bfloat16* Kp = K + (size_t)bh * NS * NDH;
  const __hip_bfloat16* Vp = Vt + (size_t)bh * NDH * NS;

  // Q as B-fragments (k32): lane holds Q[q][d = dh*32 + quad*8 + j']
  bf16x8 Bq[4][2];
#pragma unroll
  for (int g = 0; g < 4; g++)
#pragma unroll
    for (int dh = 0; dh < 2; dh++)
      Bq[g][dh] = *(const bf16x8*)(Qp + (size_t)(qbase + g * 16 + m) * NDH +
                                   dh * 32 + quad * 8);

  f32x4 accO[4][4];
  f32x4 lsum[4];
#pragma unroll
  for (int g = 0; g < 4; g++) {
    lsum[g] = (f32x4){0.f, 0.f, 0.f, 0.f};
#pragma unroll
    for (int nt = 0; nt < 4; nt++) accO[g][nt] = (f32x4){0.f, 0.f, 0.f, 0.f};
  }
  bf16x8 ones8;
#pragma unroll
  for (int i = 0; i < 8; i++) ones8[i] = (__bf16)1.0f;

  const int r8 = lane >> 3;
  const int csV = (lane & 7) ^ r8;               // V staging logical chunk
  const int csK0 = (lane & 7) ^ (r8 & 3);        // K staging, p8=0 (^4 for p8=1)
  const int krow = 8 * (m >> 2) + (m & 3);       // + c*32 + 4p at use site
  const int fK = (m & 3) ^ (((m >> 2) & 1) << 2);
  const int kc0 = (quad ^ fK) * 8;               // K chunk offset (elems)
  const int vc0 = (quad ^ (m & 7)) * 8;          // V chunk offset (elems)

#define STAGE_K(buf, tb)                                                      \
  {                                                                           \
    _Pragma("unroll") for (int p8 = 0; p8 < 2; p8++) {                        \
      const int row0 = wave * 16 + p8 * 8;                                    \
      gload16(Kp + (size_t)((tb) * 64 + row0 + r8) * NDH +                    \
                  (csK0 ^ (p8 * 4)) * 8,                                      \
              &Kt[buf][row0][0]);                                             \
    }                                                                         \
  }
#define STAGE_V(buf, tb)                                                      \
  {                                                                           \
    _Pragma("unroll") for (int p8 = 0; p8 < 2; p8++) {                        \
      const int row0 = wave * 16 + p8 * 8;                                    \
      gload16(Vp + (size_t)(row0 + r8) * NS + (tb) * 64 + csV * 8,            \
              &Vl[buf][row0][0]);                                             \
    }                                                                         \
  }

// QK chunk c from K-buf kb: 8 MFMAs -> scores a[g][p] (f32x4 each)
#define QK_CHUNK(kb, c, a)                                                    \
  {                                                                           \
    _Pragma("unroll") for (int p = 0; p < 2; p++) {                           \
      const __hip_bfloat16* kr = &Kt[kb][(c) * 32 + 4 * p + krow][0];         \
      bf16x8 k0 = *(const bf16x8*)(kr + kc0);                                 \
      bf16x8 k1 = *(const bf16x8*)(kr + (kc0 ^ 32));                          \
      _Pragma("unroll") for (int g = 0; g < 4; g++) {                         \
        f32x4 t = {0.f, 0.f, 0.f, 0.f};                                       \
        t = mfma16(k0, Bq[g][0], t);                                          \
        a[g][p] = mfma16(k1, Bq[g][1], t);                                    \
      }                                                                       \
    }                                                                         \
  }
// exp+pack chunk c of scores into P[g][c] (k32 A-layout)
#define EXP_CHUNK(c, a, P)                                                    \
  {                                                                           \
    _Pragma("unroll") for (int g = 0; g < 4; g++) {                           \
      uint4 u;                                                                \
      u.x = pack_bf16(fast_exp2(a[g][0][1]), fast_exp2(a[g][0][0]));          \
      u.y = pack_bf16(fast_exp2(a[g][0][3]), fast_exp2(a[g][0][2]));          \
      u.z = pack_bf16(fast_exp2(a[g][1][1]), fast_exp2(a[g][1][0]));          \
      u.w = pack_bf16(fast_exp2(a[g][1][3]), fast_exp2(a[g][1][2]));          \
      P[g][c] = __builtin_bit_cast(bf16x8, u);                                \
    }                                                                         \
  }
// PV for e-tiles nt0..nt0+1 from V-buf vb with P
#define PV_HALF(vb, nt0, P)                                                   \
  {                                                                           \
    _Pragma("unroll") for (int nt = (nt0); nt < (nt0) + 2; nt++) {            \
      const __hip_bfloat16* vr = &Vl[vb][nt * 16 + m][0];                     \
      bf16x8 v0 = *(const bf16x8*)(vr + vc0);                                 \
      bf16x8 v1 = *(const bf16x8*)(vr + (vc0 ^ 32));                          \
      _Pragma("unroll") for (int g = 0; g < 4; g++) {                         \
        accO[g][nt] = mfma16(P[g][0], v0, accO[g][nt]);                       \
        accO[g][nt] = mfma16(P[g][1], v1, accO[g][nt]);                       \
      }                                                                       \
    }                                                                         \
  }

  STAGE_K(0, 0); STAGE_V(0, 0);
  __syncthreads();                 // tile 0 ready
  STAGE_K(1, 1); STAGE_V(1, 1);    // prefetch tile 1

  // Prologue: QK+exp(0) -> Pp
  bf16x8 Pp[4][2];
  {
    f32x4 a[4][2];
    QK_CHUNK(0, 0, a); EXP_CHUNK(0, a, Pp);
    QK_CHUNK(0, 1, a); EXP_CHUNK(1, a, Pp);
  }

  for (int i = 1; i < 16; i++) {
    const int kb = i & 1;
    const int vb = (i - 1) % 3;
    __syncthreads();               // tile i ready (K in i&1, V in i%3)
    if (i < 15) { STAGE_K((i + 1) & 1, i + 1); STAGE_V((i + 1) % 3, i + 1); }

    bf16x8 Pc[4][2];
    f32x4 a0[4][2], a1[4][2];
    // QK(i) c=0, then PV(i-1) nt=0,1 + denom (independent MFMA to overlap
    // the exp VALU), then exp c=0; same for c=1.
    QK_CHUNK(kb, 0, a0);
#pragma unroll
    for (int g = 0; g < 4; g++) {
      lsum[g] = mfma16(Pp[g][0], ones8, lsum[g]);
      lsum[g] = mfma16(Pp[g][1], ones8, lsum[g]);
    }
    PV_HALF(vb, 0, Pp);
    EXP_CHUNK(0, a0, Pc);
    QK_CHUNK(kb, 1, a1);
    PV_HALF(vb, 2, Pp);
    EXP_CHUNK(1, a1, Pc);
#pragma unroll
    for (int g = 0; g < 4; g++) {
      Pp[g][0] = Pc[g][0];
      Pp[g][1] = Pc[g][1];
    }
  }
  // Epilogue: PV + denom for tile 15 (V-buf 15%3 = 0)
#pragma unroll
  for (int g = 0; g < 4; g++) {
    lsum[g] = mfma16(Pp[g][0], ones8, lsum[g]);
    lsum[g] = mfma16(Pp[g][1], ones8, lsum[g]);
  }
  PV_HALF(0, 0, Pp);
  PV_HALF(0, 2, Pp);

#undef STAGE_K
#undef STAGE_V
#undef QK_CHUNK
#undef EXP_CHUNK
#undef PV_HALF

  // ---- epilogue: O[q][e]/l[q]; q = quad*4+r, e = nt*16+m ----
  const int b = bh >> 4, h = bh & (NH - 1);
#pragma unroll
  for (int g = 0; g < 4; g++) {
#pragma unroll
    for (int r = 0; r < 4; r++) {
      float inv = 1.0f / lsum[g][r];
      int srow = qbase + g * 16 + quad * 4 + r;
      float* op = out + (size_t)(b * NS + srow) * ND + h * NDH;
#pragma unroll
      for (int nt = 0; nt < 4; nt++) op[nt * 16 + m] = accO[g][nt][r] * inv;
    }
  }
}

extern "C" void kernel_launch(void* const* d_in, const int* in_sizes, int n_in,
                              void* d_out, int out_size, void* d_ws, size_t ws_size,
                              hipStream_t stream) {
  const float* x  = (const float*)d_in[0];
  const float* Wq = (const float*)d_in[1];
  const float* bq = (const float*)d_in[2];
  const float* Wk = (const float*)d_in[3];
  const float* bk = (const float*)d_in[4];
  const float* Wv = (const float*)d_in[5];
  const float* bv = (const float*)d_in[6];
  float* out = (float*)d_out;

  const size_t elems = (size_t)NB * NH * NS * NDH;
  __hip_bfloat16* Qw = (__hip_bfloat16*)d_ws;
  __hip_bfloat16* Kw = Qw + elems;
  __hip_bfloat16* Vw = Kw + elems;

  qkv_proj_kernel<<<512, 256, 0, stream>>>(x, Wq, bq, Wk, bk, Wv, bv, Qw, Kw, Vw);
  // 128 (b,h) x 4 q-blocks of 256 rows, XCD-swizzled
  attn_kernel<<<512, 256, 0, stream>>>(Qw, Kw, Vw, out);
}

// Round 9
// 145.291 us; speedup vs baseline: 1.0031x; 1.0031x over previous
//
#include <hip/hip_runtime.h>
#include <hip/hip_bf16.h>

// MHA: B=8, S=1024, D=1024, H=16, DH=64.
// R9: R7's all-k32 phase-split engine at R6's occupancy. g=2 (32 q/wave),
// 1024 blocks -> 4 blocks/CU (launch_bounds(256,4)), LDS 32 KB K/V dbuf.
// Phase-split QK^T (K tile-row m <-> t = 32c + 8(m>>2) + 4p + (m&3)) puts
// exp'd P directly in k32 A-layout; PV+denominator at K=32; conflict-free
// swizzles (K: (row&3)|((row&8)>>1), V: row&7). Natural program order.

constexpr int NB = 8, NS = 1024, ND = 1024, NH = 16, NDH = 64;

typedef __bf16 bf16x8 __attribute__((ext_vector_type(8)));
typedef float f32x4 __attribute__((ext_vector_type(4)));

__device__ __forceinline__ f32x4 mfma16(bf16x8 a, bf16x8 b, f32x4 c) {
  return __builtin_amdgcn_mfma_f32_16x16x32_bf16(a, b, c, 0, 0, 0);
}

__device__ __forceinline__ float fast_exp2(float x) {
#if __has_builtin(__builtin_amdgcn_exp2f)
  return __builtin_amdgcn_exp2f(x);   // raw v_exp_f32
#else
  return __builtin_exp2f(x);
#endif
}

__device__ __forceinline__ bf16x8 cvt2bf8(float4 lo, float4 hi) {
  bf16x8 r;
  r[0] = (__bf16)lo.x; r[1] = (__bf16)lo.y; r[2] = (__bf16)lo.z; r[3] = (__bf16)lo.w;
  r[4] = (__bf16)hi.x; r[5] = (__bf16)hi.y; r[6] = (__bf16)hi.z; r[7] = (__bf16)hi.w;
  return r;
}

__device__ __forceinline__ void gload16(const __hip_bfloat16* g, __hip_bfloat16* l) {
  __builtin_amdgcn_global_load_lds(
      (const __attribute__((address_space(1))) void*)g,
      (__attribute__((address_space(3))) void*)l, 16, 0, 0);
}

// Pack two f32 into a u32 of bf16s (lo in low half): round-half-up + byte perm.
__device__ __forceinline__ unsigned pack_bf16(float hi, float lo) {
  unsigned uh = __builtin_bit_cast(unsigned, hi) + 0x8000u;
  unsigned ul = __builtin_bit_cast(unsigned, lo) + 0x8000u;
  return __builtin_amdgcn_perm(uh, ul, 0x07060302u);
}

// ---------------- QKV projection (unchanged from R3) ----------------
__global__ __launch_bounds__(256) void qkv_proj_kernel(
    const float* __restrict__ x,
    const float* __restrict__ Wq, const float* __restrict__ bq,
    const float* __restrict__ Wk, const float* __restrict__ bk,
    const float* __restrict__ Wv, const float* __restrict__ bv,
    __hip_bfloat16* __restrict__ Qo, __hip_bfloat16* __restrict__ Ko,
    __hip_bfloat16* __restrict__ Vt) {
  __shared__ __align__(16) __hip_bfloat16 Wlds[3][NDH][72];
  const int tid = threadIdx.x;
  const int wave = tid >> 6, lane = tid & 63;
  const int m = lane & 15, quad = lane >> 4;
  const int h = blockIdx.x & (NH - 1);
  const int sblk = blockIdx.x >> 4;

  const float* Ws[3] = {Wq + h * 4096, Wk + h * 4096, Wv + h * 4096};
#pragma unroll
  for (int mt = 0; mt < 3; mt++) {
#pragma unroll
    for (int p = 0; p < 4; p++) {
      int idx = (p * 256 + tid) * 4;
      float4 v = *(const float4*)(Ws[mt] + idx);
      __align__(8) __hip_bfloat16 t4[4] = {
          __float2bfloat16(v.x), __float2bfloat16(v.y),
          __float2bfloat16(v.z), __float2bfloat16(v.w)};
      *(uint2*)&Wlds[mt][idx >> 6][idx & 63] = *(const uint2*)t4;
    }
  }
  __syncthreads();

  float bq4[4][4], bk4[4][4], bvv[4];
#pragma unroll
  for (int nt = 0; nt < 4; nt++) {
    float4 a = *(const float4*)(bq + h * 64 + nt * 16 + quad * 4);
    float4 c = *(const float4*)(bk + h * 64 + nt * 16 + quad * 4);
    bq4[nt][0] = a.x; bq4[nt][1] = a.y; bq4[nt][2] = a.z; bq4[nt][3] = a.w;
    bk4[nt][0] = c.x; bk4[nt][1] = c.y; bk4[nt][2] = c.z; bk4[nt][3] = c.w;
    bvv[nt] = bv[h * 64 + nt * 16 + m];
  }

  const int rowbase = sblk * 256 + wave * 64;
  bf16x8 Xf[4][2];
#pragma unroll
  for (int st = 0; st < 4; st++) {
    const float* xp = x + (size_t)(rowbase + st * 16 + m) * ND + h * NDH + quad * 8;
#pragma unroll
    for (int c = 0; c < 2; c++) {
      float4 lo = *(const float4*)(xp + c * 32);
      float4 hi = *(const float4*)(xp + c * 32 + 4);
      Xf[st][c] = cvt2bf8(lo, hi);
    }
  }

  const int b = rowbase >> 10;
  const int s0 = rowbase & 1023;
  const float qscale = 0.18033688011112042f;  // log2(e)/sqrt(64)

#pragma unroll
  for (int mt = 0; mt < 3; mt++) {
#pragma unroll
    for (int nt = 0; nt < 4; nt++) {
      bf16x8 w0 = *(const bf16x8*)&Wlds[mt][nt * 16 + m][quad * 8];
      bf16x8 w1 = *(const bf16x8*)&Wlds[mt][nt * 16 + m][32 + quad * 8];
#pragma unroll
      for (int st = 0; st < 4; st++) {
        f32x4 acc = {0.f, 0.f, 0.f, 0.f};
        if (mt < 2) {
          acc = mfma16(w0, Xf[st][0], acc);
          acc = mfma16(w1, Xf[st][1], acc);
          const int srow = s0 + st * 16 + m;
          __align__(8) __hip_bfloat16 t4[4];
          if (mt == 0) {
#pragma unroll
            for (int r = 0; r < 4; r++)
              t4[r] = __float2bfloat16((acc[r] + bq4[nt][r]) * qscale);
            *(uint2*)(Qo + ((size_t)(b * NH + h) * NS + srow) * NDH +
                      nt * 16 + quad * 4) = *(const uint2*)t4;
          } else {
#pragma unroll
            for (int r = 0; r < 4; r++)
              t4[r] = __float2bfloat16(acc[r] + bk4[nt][r]);
            *(uint2*)(Ko + ((size_t)(b * NH + h) * NS + srow) * NDH +
                      nt * 16 + quad * 4) = *(const uint2*)t4;
          }
        } else {
          acc = mfma16(Xf[st][0], w0, acc);
          acc = mfma16(Xf[st][1], w1, acc);
          __align__(8) __hip_bfloat16 t4[4];
#pragma unroll
          for (int r = 0; r < 4; r++) t4[r] = __float2bfloat16(acc[r] + bvv[nt]);
          *(uint2*)(Vt + ((size_t)(b * NH + h) * NDH + nt * 16 + m) * NS + s0 +
                    st * 16 + quad * 4) = *(const uint2*)t4;
        }
      }
    }
  }
}

// ---------------- Attention ----------------
__global__ __launch_bounds__(256, 4) void attn_kernel(
    const __hip_bfloat16* __restrict__ Q,   // [B,H,S,DH] pre-scaled
    const __hip_bfloat16* __restrict__ K,   // [B,H,S,DH]
    const __hip_bfloat16* __restrict__ Vt,  // [B,H,DH,S]
    float* __restrict__ out) {              // [B,S,D]
  // Unpadded (global_load_lds). K swizzle f_K=(row&3)|((row&8)>>1);
  // V swizzle f_V=row&7. 32 KB total -> 4 blocks/CU.
  __shared__ __align__(16) __hip_bfloat16 Kt[2][64][64];
  __shared__ __align__(16) __hip_bfloat16 Vl[2][64][64];

  const int tid = threadIdx.x;
  const int wave = tid >> 6, lane = tid & 63;
  const int m = lane & 15, quad = lane >> 4;

  // 1024 blocks: XCD swizzle keeps one bh's 8 qblk-siblings on one XCD.
  const int xcd = blockIdx.x & 7;
  const int j = blockIdx.x >> 3;          // 0..127
  const int bh = xcd * 16 + (j & 15);
  const int qblk = j >> 4;                // 0..7
  const int qbase = qblk * 128 + wave * 32;  // 32 q-rows per wave (2 g of 16)

  const __hip_bfloat16* Qp = Q + (size_t)bh * NS * NDH;
  const __hip_bfloat16* Kp = K + (size_t)bh * NS * NDH;
  const __hip_bfloat16* Vp = Vt + (size_t)bh * NDH * NS;

  // Q as B-fragments (k32): lane holds Q[q][d = dh*32 + quad*8 + j']
  bf16x8 Bq[2][2];
#pragma unroll
  for (int g = 0; g < 2; g++)
#pragma unroll
    for (int dh = 0; dh < 2; dh++)
      Bq[g][dh] = *(const bf16x8*)(Qp + (size_t)(qbase + g * 16 + m) * NDH +
                                   dh * 32 + quad * 8);

  f32x4 accO[2][4];
  f32x4 lsum[2];
#pragma unroll
  for (int g = 0; g < 2; g++) {
    lsum[g] = (f32x4){0.f, 0.f, 0.f, 0.f};
#pragma unroll
    for (int nt = 0; nt < 4; nt++) accO[g][nt] = (f32x4){0.f, 0.f, 0.f, 0.f};
  }
  bf16x8 ones8;
#pragma unroll
  for (int i = 0; i < 8; i++) ones8[i] = (__bf16)1.0f;

  const int r8 = lane >> 3;
  const int csV = (lane & 7) ^ r8;               // V staging logical chunk
  const int csK0 = (lane & 7) ^ (r8 & 3);        // K staging, p8=0 (^4 for p8=1)
  const int krow = 8 * (m >> 2) + (m & 3);       // + c*32 + 4p at use site
  const int fK = (m & 3) ^ (((m >> 2) & 1) << 2);
  const int kc0 = (quad ^ fK) * 8;               // K chunk offset (elems)
  const int vc0 = (quad ^ (m & 7)) * 8;          // V chunk offset (elems)

#define STAGE(buf, tb)                                                        \
  {                                                                           \
    _Pragma("unroll") for (int p8 = 0; p8 < 2; p8++) {                        \
      const int row0 = wave * 16 + p8 * 8;                                    \
      gload16(Kp + (size_t)((tb) * 64 + row0 + r8) * NDH +                    \
                  (csK0 ^ (p8 * 4)) * 8,                                      \
              &Kt[buf][row0][0]);                                             \
      gload16(Vp + (size_t)(row0 + r8) * NS + (tb) * 64 + csV * 8,            \
              &Vl[buf][row0][0]);                                             \
    }                                                                         \
  }

  STAGE(0, 0);

  for (int tb = 0; tb < NS / 64; tb++) {
    const int cur = tb & 1;
    __syncthreads();  // own staging drained (vmcnt 0) + block synced
    if (tb + 1 < NS / 64) STAGE(cur ^ 1, tb + 1);  // prefetch overlaps compute

    // ---- phase-split QK^T + exp: P lands in k32 A-layout ----
    bf16x8 Pa[2][2];  // [g][c]: lane holds P[q][t = 32c + 8*quad + j]
#pragma unroll
    for (int c = 0; c < 2; c++) {
      uint2 pw[2][2];
#pragma unroll
      for (int p = 0; p < 2; p++) {
        const __hip_bfloat16* kr = &Kt[cur][c * 32 + 4 * p + krow][0];
        bf16x8 k0 = *(const bf16x8*)(kr + kc0);
        bf16x8 k1 = *(const bf16x8*)(kr + (kc0 ^ 32));
#pragma unroll
        for (int g = 0; g < 2; g++) {
          f32x4 a = {0.f, 0.f, 0.f, 0.f};
          a = mfma16(k0, Bq[g][0], a);
          a = mfma16(k1, Bq[g][1], a);
          pw[g][p].x = pack_bf16(fast_exp2(a[1]), fast_exp2(a[0]));
          pw[g][p].y = pack_bf16(fast_exp2(a[3]), fast_exp2(a[2]));
        }
      }
#pragma unroll
      for (int g = 0; g < 2; g++) {
        uint4 u = {pw[g][0].x, pw[g][0].y, pw[g][1].x, pw[g][1].y};
        Pa[g][c] = __builtin_bit_cast(bf16x8, u);
      }
    }
    // ---- denominator via ones-MFMA (k32; C rows match accO rows) ----
#pragma unroll
    for (int g = 0; g < 2; g++)
#pragma unroll
      for (int c = 0; c < 2; c++) lsum[g] = mfma16(Pa[g][c], ones8, lsum[g]);
    // ---- PV at k32: V frags contiguous b128, shared across g ----
#pragma unroll
    for (int nt = 0; nt < 4; nt++) {
      const __hip_bfloat16* vr = &Vl[cur][nt * 16 + m][0];
      bf16x8 v0 = *(const bf16x8*)(vr + vc0);
      bf16x8 v1 = *(const bf16x8*)(vr + (vc0 ^ 32));
#pragma unroll
      for (int g = 0; g < 2; g++) {
        accO[g][nt] = mfma16(Pa[g][0], v0, accO[g][nt]);
        accO[g][nt] = mfma16(Pa[g][1], v1, accO[g][nt]);
      }
    }
  }
#undef STAGE

  // ---- epilogue: O[q][e]/l[q]; q = quad*4+r, e = nt*16+m ----
  const int b = bh >> 4, h = bh & (NH - 1);
#pragma unroll
  for (int g = 0; g < 2; g++) {
#pragma unroll
    for (int r = 0; r < 4; r++) {
      float inv = 1.0f / lsum[g][r];
      int srow = qbase + g * 16 + quad * 4 + r;
      float* op = out + (size_t)(b * NS + srow) * ND + h * NDH;
#pragma unroll
      for (int nt = 0; nt < 4; nt++) op[nt * 16 + m] = accO[g][nt][r] * inv;
    }
  }
}

extern "C" void kernel_launch(void* const* d_in, const int* in_sizes, int n_in,
                              void* d_out, int out_size, void* d_ws, size_t ws_size,
                              hipStream_t stream) {
  const float* x  = (const float*)d_in[0];
  const float* Wq = (const float*)d_in[1];
  const float* bq = (const float*)d_in[2];
  const float* Wk = (const float*)d_in[3];
  const float* bk = (const float*)d_in[4];
  const float* Wv = (const float*)d_in[5];
  const float* bv = (const float*)d_in[6];
  float* out = (float*)d_out;

  const size_t elems = (size_t)NB * NH * NS * NDH;
  __hip_bfloat16* Qw = (__hip_bfloat16*)d_ws;
  __hip_bfloat16* Kw = Qw + elems;
  __hip_bfloat16* Vw = Kw + elems;

  qkv_proj_kernel<<<512, 256, 0, stream>>>(x, Wq, bq, Wk, bk, Wv, bv, Qw, Kw, Vw);
  // 128 (b,h) x 8 q-blocks of 128 rows, XCD-swizzled
  attn_kernel<<<1024, 256, 0, stream>>>(Qw, Kw, Vw, out);
}

// Round 10
// 142.210 us; speedup vs baseline: 1.0248x; 1.0217x over previous
//
#include <hip/hip_runtime.h>
#include <hip/hip_bf16.h>

// MHA: B=8, S=1024, D=1024, H=16, DH=64.
// R10: R7's all-k32 phase-split attention (best measured: 44.8 us; 512 blocks,
// g=4, conflict-free swizzles, P in registers) + v_cvt_pk_bf16_f32 packing
// (1 VALU per 2 scores vs 3) in attn softmax and proj stores. R6/R8/R9
// established occupancy/manual-interleave don't help; VALU cycles do.

constexpr int NB = 8, NS = 1024, ND = 1024, NH = 16, NDH = 64;

typedef __bf16 bf16x8 __attribute__((ext_vector_type(8)));
typedef __bf16 bf16x2 __attribute__((ext_vector_type(2)));
typedef float f32x4 __attribute__((ext_vector_type(4)));

__device__ __forceinline__ f32x4 mfma16(bf16x8 a, bf16x8 b, f32x4 c) {
  return __builtin_amdgcn_mfma_f32_16x16x32_bf16(a, b, c, 0, 0, 0);
}

__device__ __forceinline__ float fast_exp2(float x) {
#if __has_builtin(__builtin_amdgcn_exp2f)
  return __builtin_amdgcn_exp2f(x);   // raw v_exp_f32
#else
  return __builtin_exp2f(x);
#endif
}

// Pack two f32 -> u32 of bf16s (lo in low half).
__device__ __forceinline__ unsigned pack2(float lo, float hi) {
#if __has_builtin(__builtin_amdgcn_cvt_pk_bf16_f32)
  bf16x2 v = __builtin_amdgcn_cvt_pk_bf16_f32(lo, hi);
  return __builtin_bit_cast(unsigned, v);
#else
  unsigned uh = __builtin_bit_cast(unsigned, hi) + 0x8000u;
  unsigned ul = __builtin_bit_cast(unsigned, lo) + 0x8000u;
  return __builtin_amdgcn_perm(uh, ul, 0x07060302u);
#endif
}

__device__ __forceinline__ bf16x8 cvt2bf8(float4 lo, float4 hi) {
  bf16x8 r;
  r[0] = (__bf16)lo.x; r[1] = (__bf16)lo.y; r[2] = (__bf16)lo.z; r[3] = (__bf16)lo.w;
  r[4] = (__bf16)hi.x; r[5] = (__bf16)hi.y; r[6] = (__bf16)hi.z; r[7] = (__bf16)hi.w;
  return r;
}

__device__ __forceinline__ void gload16(const __hip_bfloat16* g, __hip_bfloat16* l) {
  __builtin_amdgcn_global_load_lds(
      (const __attribute__((address_space(1))) void*)g,
      (__attribute__((address_space(3))) void*)l, 16, 0, 0);
}

// ---------------- QKV projection ----------------
__global__ __launch_bounds__(256) void qkv_proj_kernel(
    const float* __restrict__ x,
    const float* __restrict__ Wq, const float* __restrict__ bq,
    const float* __restrict__ Wk, const float* __restrict__ bk,
    const float* __restrict__ Wv, const float* __restrict__ bv,
    __hip_bfloat16* __restrict__ Qo, __hip_bfloat16* __restrict__ Ko,
    __hip_bfloat16* __restrict__ Vt) {
  __shared__ __align__(16) __hip_bfloat16 Wlds[3][NDH][72];
  const int tid = threadIdx.x;
  const int wave = tid >> 6, lane = tid & 63;
  const int m = lane & 15, quad = lane >> 4;
  const int h = blockIdx.x & (NH - 1);
  const int sblk = blockIdx.x >> 4;

  const float* Ws[3] = {Wq + h * 4096, Wk + h * 4096, Wv + h * 4096};
#pragma unroll
  for (int mt = 0; mt < 3; mt++) {
#pragma unroll
    for (int p = 0; p < 4; p++) {
      int idx = (p * 256 + tid) * 4;
      float4 v = *(const float4*)(Ws[mt] + idx);
      uint2 w;
      w.x = pack2(v.x, v.y);
      w.y = pack2(v.z, v.w);
      *(uint2*)&Wlds[mt][idx >> 6][idx & 63] = w;
    }
  }
  __syncthreads();

  float bq4[4][4], bk4[4][4], bvv[4];
#pragma unroll
  for (int nt = 0; nt < 4; nt++) {
    float4 a = *(const float4*)(bq + h * 64 + nt * 16 + quad * 4);
    float4 c = *(const float4*)(bk + h * 64 + nt * 16 + quad * 4);
    bq4[nt][0] = a.x; bq4[nt][1] = a.y; bq4[nt][2] = a.z; bq4[nt][3] = a.w;
    bk4[nt][0] = c.x; bk4[nt][1] = c.y; bk4[nt][2] = c.z; bk4[nt][3] = c.w;
    bvv[nt] = bv[h * 64 + nt * 16 + m];
  }

  const int rowbase = sblk * 256 + wave * 64;
  bf16x8 Xf[4][2];
#pragma unroll
  for (int st = 0; st < 4; st++) {
    const float* xp = x + (size_t)(rowbase + st * 16 + m) * ND + h * NDH + quad * 8;
#pragma unroll
    for (int c = 0; c < 2; c++) {
      float4 lo = *(const float4*)(xp + c * 32);
      float4 hi = *(const float4*)(xp + c * 32 + 4);
      Xf[st][c] = cvt2bf8(lo, hi);
    }
  }

  const int b = rowbase >> 10;
  const int s0 = rowbase & 1023;
  const float qscale = 0.18033688011112042f;  // log2(e)/sqrt(64)

#pragma unroll
  for (int mt = 0; mt < 3; mt++) {
#pragma unroll
    for (int nt = 0; nt < 4; nt++) {
      bf16x8 w0 = *(const bf16x8*)&Wlds[mt][nt * 16 + m][quad * 8];
      bf16x8 w1 = *(const bf16x8*)&Wlds[mt][nt * 16 + m][32 + quad * 8];
#pragma unroll
      for (int st = 0; st < 4; st++) {
        f32x4 acc = {0.f, 0.f, 0.f, 0.f};
        if (mt < 2) {
          // D = W · x^T: lane holds s = m, e = nt*16 + quad*4 + r
          acc = mfma16(w0, Xf[st][0], acc);
          acc = mfma16(w1, Xf[st][1], acc);
          const int srow = s0 + st * 16 + m;
          uint2 w;
          if (mt == 0) {
            w.x = pack2((acc[0] + bq4[nt][0]) * qscale, (acc[1] + bq4[nt][1]) * qscale);
            w.y = pack2((acc[2] + bq4[nt][2]) * qscale, (acc[3] + bq4[nt][3]) * qscale);
            *(uint2*)(Qo + ((size_t)(b * NH + h) * NS + srow) * NDH +
                      nt * 16 + quad * 4) = w;
          } else {
            w.x = pack2(acc[0] + bk4[nt][0], acc[1] + bk4[nt][1]);
            w.y = pack2(acc[2] + bk4[nt][2], acc[3] + bk4[nt][3]);
            *(uint2*)(Ko + ((size_t)(b * NH + h) * NS + srow) * NDH +
                      nt * 16 + quad * 4) = w;
          }
        } else {
          // D = x · W^T: lane holds e = nt*16+m, s = quad*4+r
          acc = mfma16(Xf[st][0], w0, acc);
          acc = mfma16(Xf[st][1], w1, acc);
          uint2 w;
          w.x = pack2(acc[0] + bvv[nt], acc[1] + bvv[nt]);
          w.y = pack2(acc[2] + bvv[nt], acc[3] + bvv[nt]);
          *(uint2*)(Vt + ((size_t)(b * NH + h) * NDH + nt * 16 + m) * NS + s0 +
                    st * 16 + quad * 4) = w;
        }
      }
    }
  }
}

// ---------------- Attention ----------------
__global__ __launch_bounds__(256, 2) void attn_kernel(
    const __hip_bfloat16* __restrict__ Q,   // [B,H,S,DH] pre-scaled
    const __hip_bfloat16* __restrict__ K,   // [B,H,S,DH]
    const __hip_bfloat16* __restrict__ Vt,  // [B,H,DH,S]
    float* __restrict__ out) {              // [B,S,D]
  // Unpadded (global_load_lds). K swizzle f_K=(row&3)|((row&8)>>1);
  // V swizzle f_V=row&7. 32 KB total.
  __shared__ __align__(16) __hip_bfloat16 Kt[2][64][64];
  __shared__ __align__(16) __hip_bfloat16 Vl[2][64][64];

  const int tid = threadIdx.x;
  const int wave = tid >> 6, lane = tid & 63;
  const int m = lane & 15, quad = lane >> 4;

  const int xcd = blockIdx.x & 7;
  const int j = blockIdx.x >> 3;          // 0..63
  const int bh = xcd * 16 + (j & 15);
  const int qblk = j >> 4;                // 0..3
  const int qbase = qblk * 256 + wave * 64;  // 64 q-rows per wave (4 g of 16)

  const __hip_bfloat16* Qp = Q + (size_t)bh * NS * NDH;
  const __hip_bfloat16* Kp = K + (size_t)bh * NS * NDH;
  const __hip_bfloat16* Vp = Vt + (size_t)bh * NDH * NS;

  // Q as B-fragments (k32): lane holds Q[q][d = dh*32 + quad*8 + j']
  bf16x8 Bq[4][2];
#pragma unroll
  for (int g = 0; g < 4; g++)
#pragma unroll
    for (int dh = 0; dh < 2; dh++)
      Bq[g][dh] = *(const bf16x8*)(Qp + (size_t)(qbase + g * 16 + m) * NDH +
                                   dh * 32 + quad * 8);

  f32x4 accO[4][4];
  f32x4 lsum[4];
#pragma unroll
  for (int g = 0; g < 4; g++) {
    lsum[g] = (f32x4){0.f, 0.f, 0.f, 0.f};
#pragma unroll
    for (int nt = 0; nt < 4; nt++) accO[g][nt] = (f32x4){0.f, 0.f, 0.f, 0.f};
  }
  bf16x8 ones8;
#pragma unroll
  for (int i = 0; i < 8; i++) ones8[i] = (__bf16)1.0f;

  const int r8 = lane >> 3;
  const int csV = (lane & 7) ^ r8;               // V staging logical chunk
  const int csK0 = (lane & 7) ^ (r8 & 3);        // K staging, p8=0 (^4 for p8=1)
  const int krow = 8 * (m >> 2) + (m & 3);       // + c*32 + 4p at use site
  const int fK = (m & 3) ^ (((m >> 2) & 1) << 2);
  const int kc0 = (quad ^ fK) * 8;               // K chunk offset (elems)
  const int vc0 = (quad ^ (m & 7)) * 8;          // V chunk offset (elems)

#define STAGE(buf, tb)                                                        \
  {                                                                           \
    _Pragma("unroll") for (int p8 = 0; p8 < 2; p8++) {                        \
      const int row0 = wave * 16 + p8 * 8;                                    \
      gload16(Kp + (size_t)((tb) * 64 + row0 + r8) * NDH +                    \
                  (csK0 ^ (p8 * 4)) * 8,                                      \
              &Kt[buf][row0][0]);                                             \
      gload16(Vp + (size_t)(row0 + r8) * NS + (tb) * 64 + csV * 8,            \
              &Vl[buf][row0][0]);                                             \
    }                                                                         \
  }

  STAGE(0, 0);

  for (int tb = 0; tb < NS / 64; tb++) {
    const int cur = tb & 1;
    __syncthreads();  // own staging drained (vmcnt 0) + block synced
    if (tb + 1 < NS / 64) STAGE(cur ^ 1, tb + 1);  // prefetch overlaps compute

    // ---- phase-split QK^T + exp: P lands in k32 A-layout ----
    bf16x8 Pa[4][2];  // [g][c]: lane holds P[q][t = 32c + 8*quad + j]
#pragma unroll
    for (int c = 0; c < 2; c++) {
      uint2 pw[4][2];
#pragma unroll
      for (int p = 0; p < 2; p++) {
        const __hip_bfloat16* kr = &Kt[cur][c * 32 + 4 * p + krow][0];
        bf16x8 k0 = *(const bf16x8*)(kr + kc0);
        bf16x8 k1 = *(const bf16x8*)(kr + (kc0 ^ 32));
#pragma unroll
        for (int g = 0; g < 4; g++) {
          f32x4 a = {0.f, 0.f, 0.f, 0.f};
          a = mfma16(k0, Bq[g][0], a);
          a = mfma16(k1, Bq[g][1], a);
          pw[g][p].x = pack2(fast_exp2(a[0]), fast_exp2(a[1]));
          pw[g][p].y = pack2(fast_exp2(a[2]), fast_exp2(a[3]));
        }
      }
#pragma unroll
      for (int g = 0; g < 4; g++) {
        uint4 u = {pw[g][0].x, pw[g][0].y, pw[g][1].x, pw[g][1].y};
        Pa[g][c] = __builtin_bit_cast(bf16x8, u);
      }
    }
    // ---- denominator via ones-MFMA (k32; C rows match accO rows) ----
#pragma unroll
    for (int g = 0; g < 4; g++)
#pragma unroll
      for (int c = 0; c < 2; c++) lsum[g] = mfma16(Pa[g][c], ones8, lsum[g]);
    // ---- PV at k32: V frags contiguous b128, shared across g ----
#pragma unroll
    for (int nt = 0; nt < 4; nt++) {
      const __hip_bfloat16* vr = &Vl[cur][nt * 16 + m][0];
      bf16x8 v0 = *(const bf16x8*)(vr + vc0);
      bf16x8 v1 = *(const bf16x8*)(vr + (vc0 ^ 32));
#pragma unroll
      for (int g = 0; g < 4; g++) {
        accO[g][nt] = mfma16(Pa[g][0], v0, accO[g][nt]);
        accO[g][nt] = mfma16(Pa[g][1], v1, accO[g][nt]);
      }
    }
  }
#undef STAGE

  // ---- epilogue: O[q][e]/l[q]; q = quad*4+r, e = nt*16+m ----
  const int b = bh >> 4, h = bh & (NH - 1);
#pragma unroll
  for (int g = 0; g < 4; g++) {
#pragma unroll
    for (int r = 0; r < 4; r++) {
      float inv = 1.0f / lsum[g][r];
      int srow = qbase + g * 16 + quad * 4 + r;
      float* op = out + (size_t)(b * NS + srow) * ND + h * NDH;
#pragma unroll
      for (int nt = 0; nt < 4; nt++) op[nt * 16 + m] = accO[g][nt][r] * inv;
    }
  }
}

extern "C" void kernel_launch(void* const* d_in, const int* in_sizes, int n_in,
                              void* d_out, int out_size, void* d_ws, size_t ws_size,
                              hipStream_t stream) {
  const float* x  = (const float*)d_in[0];
  const float* Wq = (const float*)d_in[1];
  const float* bq = (const float*)d_in[2];
  const float* Wk = (const float*)d_in[3];
  const float* bk = (const float*)d_in[4];
  const float* Wv = (const float*)d_in[5];
  const float* bv = (const float*)d_in[6];
  float* out = (float*)d_out;

  const size_t elems = (size_t)NB * NH * NS * NDH;
  __hip_bfloat16* Qw = (__hip_bfloat16*)d_ws;
  __hip_bfloat16* Kw = Qw + elems;
  __hip_bfloat16* Vw = Kw + elems;

  qkv_proj_kernel<<<512, 256, 0, stream>>>(x, Wq, bq, Wk, bk, Wv, bv, Qw, Kw, Vw);
  // 128 (b,h) x 4 q-blocks of 256 rows, XCD-swizzled
  attn_kernel<<<512, 256, 0, stream>>>(Qw, Kw, Vw, out);
}

// Round 11
// 140.288 us; speedup vs baseline: 1.0389x; 1.0137x over previous
//
#include <hip/hip_runtime.h>
#include <hip/hip_bf16.h>

// MHA: B=8, S=1024, D=1024, H=16, DH=64.
// R11: R7/R10 all-k32 phase-split engine + VALU/barrier trim:
//  - truncation bf16 pack for P (1 v_perm per 2 scores; bias cancels in
//    numerator/denominator since the ones-MFMA denominator uses the SAME
//    truncated P),
//  - TB=128 t-tiles (half the barriers; compute in two 64-t sub-phases so
//    register pressure is unchanged), K swizzle f_K=(row&3)|((row&8)>>1),
//    V swizzle phys_chunk = chunk ^ (e&15) — all LDS ops <=2-way,
//  - Pa dwords built in place, persistent zero C-operand.

constexpr int NB = 8, NS = 1024, ND = 1024, NH = 16, NDH = 64;

typedef __bf16 bf16x8 __attribute__((ext_vector_type(8)));
typedef float f32x4 __attribute__((ext_vector_type(4)));

__device__ __forceinline__ f32x4 mfma16(bf16x8 a, bf16x8 b, f32x4 c) {
  return __builtin_amdgcn_mfma_f32_16x16x32_bf16(a, b, c, 0, 0, 0);
}

__device__ __forceinline__ float fast_exp2(float x) {
#if __has_builtin(__builtin_amdgcn_exp2f)
  return __builtin_amdgcn_exp2f(x);   // raw v_exp_f32
#else
  return __builtin_exp2f(x);
#endif
}

// RNE-ish pack (round-half-up) — used in proj where cost is negligible.
__device__ __forceinline__ unsigned pack2(float lo, float hi) {
  unsigned uh = __builtin_bit_cast(unsigned, hi) + 0x8000u;
  unsigned ul = __builtin_bit_cast(unsigned, lo) + 0x8000u;
  return __builtin_amdgcn_perm(uh, ul, 0x07060302u);
}

// Truncation pack — 1 VALU; used for P (bias cancels num/den).
__device__ __forceinline__ unsigned pack2t(float lo, float hi) {
  return __builtin_amdgcn_perm(__builtin_bit_cast(unsigned, hi),
                               __builtin_bit_cast(unsigned, lo), 0x07060302u);
}

__device__ __forceinline__ bf16x8 cvt2bf8(float4 lo, float4 hi) {
  bf16x8 r;
  r[0] = (__bf16)lo.x; r[1] = (__bf16)lo.y; r[2] = (__bf16)lo.z; r[3] = (__bf16)lo.w;
  r[4] = (__bf16)hi.x; r[5] = (__bf16)hi.y; r[6] = (__bf16)hi.z; r[7] = (__bf16)hi.w;
  return r;
}

__device__ __forceinline__ void gload16(const __hip_bfloat16* g, __hip_bfloat16* l) {
  __builtin_amdgcn_global_load_lds(
      (const __attribute__((address_space(1))) void*)g,
      (__attribute__((address_space(3))) void*)l, 16, 0, 0);
}

// ---------------- QKV projection (unchanged from R10) ----------------
__global__ __launch_bounds__(256) void qkv_proj_kernel(
    const float* __restrict__ x,
    const float* __restrict__ Wq, const float* __restrict__ bq,
    const float* __restrict__ Wk, const float* __restrict__ bk,
    const float* __restrict__ Wv, const float* __restrict__ bv,
    __hip_bfloat16* __restrict__ Qo, __hip_bfloat16* __restrict__ Ko,
    __hip_bfloat16* __restrict__ Vt) {
  __shared__ __align__(16) __hip_bfloat16 Wlds[3][NDH][72];
  const int tid = threadIdx.x;
  const int wave = tid >> 6, lane = tid & 63;
  const int m = lane & 15, quad = lane >> 4;
  const int h = blockIdx.x & (NH - 1);
  const int sblk = blockIdx.x >> 4;

  const float* Ws[3] = {Wq + h * 4096, Wk + h * 4096, Wv + h * 4096};
#pragma unroll
  for (int mt = 0; mt < 3; mt++) {
#pragma unroll
    for (int p = 0; p < 4; p++) {
      int idx = (p * 256 + tid) * 4;
      float4 v = *(const float4*)(Ws[mt] + idx);
      uint2 w;
      w.x = pack2(v.x, v.y);
      w.y = pack2(v.z, v.w);
      *(uint2*)&Wlds[mt][idx >> 6][idx & 63] = w;
    }
  }
  __syncthreads();

  float bq4[4][4], bk4[4][4], bvv[4];
#pragma unroll
  for (int nt = 0; nt < 4; nt++) {
    float4 a = *(const float4*)(bq + h * 64 + nt * 16 + quad * 4);
    float4 c = *(const float4*)(bk + h * 64 + nt * 16 + quad * 4);
    bq4[nt][0] = a.x; bq4[nt][1] = a.y; bq4[nt][2] = a.z; bq4[nt][3] = a.w;
    bk4[nt][0] = c.x; bk4[nt][1] = c.y; bk4[nt][2] = c.z; bk4[nt][3] = c.w;
    bvv[nt] = bv[h * 64 + nt * 16 + m];
  }

  const int rowbase = sblk * 256 + wave * 64;
  bf16x8 Xf[4][2];
#pragma unroll
  for (int st = 0; st < 4; st++) {
    const float* xp = x + (size_t)(rowbase + st * 16 + m) * ND + h * NDH + quad * 8;
#pragma unroll
    for (int c = 0; c < 2; c++) {
      float4 lo = *(const float4*)(xp + c * 32);
      float4 hi = *(const float4*)(xp + c * 32 + 4);
      Xf[st][c] = cvt2bf8(lo, hi);
    }
  }

  const int b = rowbase >> 10;
  const int s0 = rowbase & 1023;
  const float qscale = 0.18033688011112042f;  // log2(e)/sqrt(64)

#pragma unroll
  for (int mt = 0; mt < 3; mt++) {
#pragma unroll
    for (int nt = 0; nt < 4; nt++) {
      bf16x8 w0 = *(const bf16x8*)&Wlds[mt][nt * 16 + m][quad * 8];
      bf16x8 w1 = *(const bf16x8*)&Wlds[mt][nt * 16 + m][32 + quad * 8];
#pragma unroll
      for (int st = 0; st < 4; st++) {
        f32x4 acc = {0.f, 0.f, 0.f, 0.f};
        if (mt < 2) {
          acc = mfma16(w0, Xf[st][0], acc);
          acc = mfma16(w1, Xf[st][1], acc);
          const int srow = s0 + st * 16 + m;
          uint2 w;
          if (mt == 0) {
            w.x = pack2((acc[0] + bq4[nt][0]) * qscale, (acc[1] + bq4[nt][1]) * qscale);
            w.y = pack2((acc[2] + bq4[nt][2]) * qscale, (acc[3] + bq4[nt][3]) * qscale);
            *(uint2*)(Qo + ((size_t)(b * NH + h) * NS + srow) * NDH +
                      nt * 16 + quad * 4) = w;
          } else {
            w.x = pack2(acc[0] + bk4[nt][0], acc[1] + bk4[nt][1]);
            w.y = pack2(acc[2] + bk4[nt][2], acc[3] + bk4[nt][3]);
            *(uint2*)(Ko + ((size_t)(b * NH + h) * NS + srow) * NDH +
                      nt * 16 + quad * 4) = w;
          }
        } else {
          acc = mfma16(Xf[st][0], w0, acc);
          acc = mfma16(Xf[st][1], w1, acc);
          uint2 w;
          w.x = pack2(acc[0] + bvv[nt], acc[1] + bvv[nt]);
          w.y = pack2(acc[2] + bvv[nt], acc[3] + bvv[nt]);
          *(uint2*)(Vt + ((size_t)(b * NH + h) * NDH + nt * 16 + m) * NS + s0 +
                    st * 16 + quad * 4) = w;
        }
      }
    }
  }
}

// ---------------- Attention ----------------
__global__ __launch_bounds__(256, 2) void attn_kernel(
    const __hip_bfloat16* __restrict__ Q,   // [B,H,S,DH] pre-scaled
    const __hip_bfloat16* __restrict__ K,   // [B,H,S,DH]
    const __hip_bfloat16* __restrict__ Vt,  // [B,H,DH,S]
    float* __restrict__ out) {              // [B,S,D]
  // TB=128 double-buffered: K 2x16KB + V 2x16KB = 64 KB -> 2 blocks/CU.
  __shared__ __align__(16) __hip_bfloat16 Kt[2][128][64];
  __shared__ __align__(16) __hip_bfloat16 Vl[2][64][128];

  const int tid = threadIdx.x;
  const int wave = tid >> 6, lane = tid & 63;
  const int m = lane & 15, quad = lane >> 4;

  const int xcd = blockIdx.x & 7;
  const int j = blockIdx.x >> 3;          // 0..63
  const int bh = xcd * 16 + (j & 15);
  const int qblk = j >> 4;                // 0..3
  const int qbase = qblk * 256 + wave * 64;  // 64 q-rows per wave (4 g of 16)

  const __hip_bfloat16* Qp = Q + (size_t)bh * NS * NDH;
  const __hip_bfloat16* Kp = K + (size_t)bh * NS * NDH;
  const __hip_bfloat16* Vp = Vt + (size_t)bh * NDH * NS;

  // Q as B-fragments (k32): lane holds Q[q][d = dh*32 + quad*8 + j']
  bf16x8 Bq[4][2];
#pragma unroll
  for (int g = 0; g < 4; g++)
#pragma unroll
    for (int dh = 0; dh < 2; dh++)
      Bq[g][dh] = *(const bf16x8*)(Qp + (size_t)(qbase + g * 16 + m) * NDH +
                                   dh * 32 + quad * 8);

  f32x4 accO[4][4];
  f32x4 lsum[4];
#pragma unroll
  for (int g = 0; g < 4; g++) {
    lsum[g] = (f32x4){0.f, 0.f, 0.f, 0.f};
#pragma unroll
    for (int nt = 0; nt < 4; nt++) accO[g][nt] = (f32x4){0.f, 0.f, 0.f, 0.f};
  }
  bf16x8 ones8;
#pragma unroll
  for (int i = 0; i < 8; i++) ones8[i] = (__bf16)1.0f;
  const f32x4 fzero = {0.f, 0.f, 0.f, 0.f};

  // Frag-read constants (per lane):
  const int krow = 8 * (m >> 2) + (m & 3);       // + tc*32 + 4p at use site
  const int fK = (m & 3) ^ (((m >> 2) & 1) << 2);
  const int kc0 = (quad ^ fK) * 8;               // K chunk offset (elems)
  const int vq = quad ^ (m & 3);                 // V phys chunk low bits
  const int vm2 = (m >> 2) & 3;                  // V phys chunk high-bit mixer

  // Staging: per wave 4 K-lines (8 rows x 8 chunks) + 4 V-lines (4 rows x 16).
#define STAGE(buf, tb)                                                        \
  {                                                                           \
    _Pragma("unroll") for (int l = 0; l < 4; l++) {                           \
      const int krb = wave * 32 + l * 8;                                      \
      const int csK = (lane & 7) ^ ((lane >> 3) & 3) ^ ((l & 1) << 2);        \
      gload16(Kp + (size_t)((tb) * 128 + krb + (lane >> 3)) * NDH + csK * 8,  \
              &Kt[buf][krb][0]);                                              \
      const int vrb = wave * 16 + l * 4;                                      \
      const int csVl = (lane & 15) ^ (l * 4 + (lane >> 4));                   \
      gload16(Vp + (size_t)(vrb + (lane >> 4)) * NS + (tb) * 128 + csVl * 8,  \
              &Vl[buf][vrb][0]);                                              \
    }                                                                         \
  }

  STAGE(0, 0);

  for (int tb = 0; tb < 8; tb++) {
    const int cur = tb & 1;
    __syncthreads();  // own staging drained (vmcnt 0) + block synced
    if (tb + 1 < 8) STAGE(cur ^ 1, tb + 1);  // prefetch overlaps compute

#pragma unroll
    for (int h64 = 0; h64 < 2; h64++) {  // two 64-t sub-phases per tile
      // ---- phase-split QK^T + exp: P lands in k32 A-layout ----
      bf16x8 Pa[4][2];  // [g][c]: lane holds P[q][t = (h64*2+c)*32 + 8*quad + j]
#pragma unroll
      for (int c = 0; c < 2; c++) {
        uint4 u[4];
#pragma unroll
        for (int p = 0; p < 2; p++) {
          const __hip_bfloat16* kr =
              &Kt[cur][h64 * 64 + c * 32 + 4 * p + krow][0];
          bf16x8 k0 = *(const bf16x8*)(kr + kc0);
          bf16x8 k1 = *(const bf16x8*)(kr + (kc0 ^ 32));
#pragma unroll
          for (int g = 0; g < 4; g++) {
            f32x4 a = mfma16(k1, Bq[g][1], mfma16(k0, Bq[g][0], fzero));
            unsigned w0 = pack2t(fast_exp2(a[0]), fast_exp2(a[1]));
            unsigned w1 = pack2t(fast_exp2(a[2]), fast_exp2(a[3]));
            if (p == 0) { u[g].x = w0; u[g].y = w1; }
            else        { u[g].z = w0; u[g].w = w1; }
          }
        }
#pragma unroll
        for (int g = 0; g < 4; g++) Pa[g][c] = __builtin_bit_cast(bf16x8, u[g]);
      }
      // ---- denominator via ones-MFMA (k32; C rows match accO rows) ----
#pragma unroll
      for (int g = 0; g < 4; g++)
#pragma unroll
        for (int c = 0; c < 2; c++) lsum[g] = mfma16(Pa[g][c], ones8, lsum[g]);
      // ---- PV at k32: V frags b128, shared across g ----
#pragma unroll
      for (int nt = 0; nt < 4; nt++) {
#pragma unroll
        for (int c = 0; c < 2; c++) {
          const int tb4 = h64 * 2 + c;
          const int off = (((tb4 ^ vm2) << 2) | vq) << 3;
          bf16x8 v = *(const bf16x8*)&Vl[cur][nt * 16 + m][off];
#pragma unroll
          for (int g = 0; g < 4; g++)
            accO[g][nt] = mfma16(Pa[g][c], v, accO[g][nt]);
        }
      }
    }
  }
#undef STAGE

  // ---- epilogue: O[q][e]/l[q]; q = quad*4+r, e = nt*16+m ----
  const int b = bh >> 4, h = bh & (NH - 1);
#pragma unroll
  for (int g = 0; g < 4; g++) {
#pragma unroll
    for (int r = 0; r < 4; r++) {
      float inv = 1.0f / lsum[g][r];
      int srow = qbase + g * 16 + quad * 4 + r;
      float* op = out + (size_t)(b * NS + srow) * ND + h * NDH;
#pragma unroll
      for (int nt = 0; nt < 4; nt++) op[nt * 16 + m] = accO[g][nt][r] * inv;
    }
  }
}

extern "C" void kernel_launch(void* const* d_in, const int* in_sizes, int n_in,
                              void* d_out, int out_size, void* d_ws, size_t ws_size,
                              hipStream_t stream) {
  const float* x  = (const float*)d_in[0];
  const float* Wq = (const float*)d_in[1];
  const float* bq = (const float*)d_in[2];
  const float* Wk = (const float*)d_in[3];
  const float* bk = (const float*)d_in[4];
  const float* Wv = (const float*)d_in[5];
  const float* bv = (const float*)d_in[6];
  float* out = (float*)d_out;

  const size_t elems = (size_t)NB * NH * NS * NDH;
  __hip_bfloat16* Qw = (__hip_bfloat16*)d_ws;
  __hip_bfloat16* Kw = Qw + elems;
  __hip_bfloat16* Vw = Kw + elems;

  qkv_proj_kernel<<<512, 256, 0, stream>>>(x, Wq, bq, Wk, bk, Wv, bv, Qw, Kw, Vw);
  // 128 (b,h) x 4 q-blocks of 256 rows, XCD-swizzled
  attn_kernel<<<512, 256, 0, stream>>>(Qw, Kw, Vw, out);
}